// Round 1
// baseline (371.839 us; speedup 1.0000x reference)
//
#include <hip/hip_runtime.h>
#include <stdint.h>

#define M_TOT 8192
#define K_TOT 4096
#define N_TOT 4096
#define GROUPQ 32

#define BM 128
#define BN 128
#define BK 32

typedef __bf16 bf16x8 __attribute__((ext_vector_type(8)));
typedef float f32x4 __attribute__((ext_vector_type(4)));
typedef unsigned short u16;
typedef unsigned short u16x8 __attribute__((ext_vector_type(8)));

__device__ __forceinline__ u16 f2bf_rne(float f) {
  union { float f; uint32_t u; } v; v.f = f;
  uint32_t u = v.u;
  uint32_t r = (u + 0x7FFFu + ((u >> 16) & 1u)) >> 16;  // round-nearest-even
  return (u16)r;
}

// ---- prepass 1: x fp32 -> bf16 (8 elems/thread, 32B in / 16B out) ----
__global__ void cvt_x_kernel(const float* __restrict__ x, u16* __restrict__ xb, int n8) {
  int stride = gridDim.x * blockDim.x;
  for (int i = blockIdx.x * blockDim.x + threadIdx.x; i < n8; i += stride) {
    const float4* p = (const float4*)(x + (size_t)i * 8);
    float4 a = p[0];
    float4 b = p[1];
    u16x8 o;
    o[0] = f2bf_rne(a.x); o[1] = f2bf_rne(a.y); o[2] = f2bf_rne(a.z); o[3] = f2bf_rne(a.w);
    o[4] = f2bf_rne(b.x); o[5] = f2bf_rne(b.y); o[6] = f2bf_rne(b.z); o[7] = f2bf_rne(b.w);
    *(u16x8*)(xb + (size_t)i * 8) = o;
  }
}

// ---- prepass 2: dequant packed nibbles -> bf16 W[N][K] row-major ----
// 8 int32 (16 output elems) per thread; 16-elem chunk never straddles a
// 32-elem scale group (chunks are 16-aligned), so one scale per thread.
__global__ void dequant_w_kernel(const int* __restrict__ wp, const float* __restrict__ sc,
                                 u16* __restrict__ wb) {
  const int KH = K_TOT / 2;              // 2048 packed ints per row
  const int total = N_TOT * KH / 8;
  int stride = gridDim.x * blockDim.x;
  for (int t = blockIdx.x * blockDim.x + threadIdx.x; t < total; t += stride) {
    int base = t * 8;                    // int index
    int o = base >> 11;                  // / 2048
    int ci = base & 2047;
    int e0 = ci * 2;                     // first output element index
    float scale = sc[o * (K_TOT / GROUPQ) + (e0 >> 5)];
    int4 p0 = *(const int4*)(wp + base);
    int4 p1 = *(const int4*)(wp + base + 4);
    int v[8] = {p0.x, p0.y, p0.z, p0.w, p1.x, p1.y, p1.z, p1.w};
    u16x8 oA, oB;
#pragma unroll
    for (int j = 0; j < 8; ++j) {
      float lo = (float)((v[j] & 0xF) - 8) * scale;
      float hi = (float)(((v[j] >> 4) & 0xF) - 8) * scale;
      u16 lob = f2bf_rne(lo), hib = f2bf_rne(hi);
      if (j < 4) { oA[2 * j] = lob; oA[2 * j + 1] = hib; }
      else       { oB[2 * (j - 4)] = lob; oB[2 * (j - 4) + 1] = hib; }
    }
    u16* dst = wb + (size_t)o * K_TOT + e0;
    *(u16x8*)dst = oA;
    *(u16x8*)(dst + 8) = oB;
  }
}

// ---- main GEMM: C[M][N] = A[M][K] * Bt[N][K]^T + bias, bf16 MFMA ----
// m97 structure: 128x128 tile, BK=32, 4 waves (2x2), 4x4 16x16x32 frags/wave,
// global_load_lds width=16 staging, linear LDS, 2 barriers per K-step.
__global__ __launch_bounds__(256) void gemm_bf16_kernel(
    const u16* __restrict__ A, const u16* __restrict__ Bt,
    const float* __restrict__ bias, float* __restrict__ C) {
  __shared__ u16 sA[BM * BK];  // 8 KiB
  __shared__ u16 sB[BN * BK];  // 8 KiB

  const int ntn = N_TOT / BN;  // 32
  int nwg = gridDim.x;         // 2048, divisible by 8
  int cpx = nwg >> 3;
  int wg = blockIdx.x;
  int swz = (wg & 7) * cpx + (wg >> 3);  // XCD-aware, bijective (nwg%8==0)
  int bm = swz / ntn, bn = swz % ntn;

  int tid = threadIdx.x;
  int w = tid >> 6;
  int lane = tid & 63;
  int wr = w >> 1, wc = w & 1;

  f32x4 acc[4][4] = {};

  const u16* Abase = A + (size_t)(bm * BM) * K_TOT;
  const u16* Bbase = Bt + (size_t)(bn * BN) * K_TOT;

  // staging: wave w, inst i covers LDS rows (w*2+i)*16..+15; lane l writes
  // 16B at lds_base + l*16 -> row +=l/4, k-chunk (l&3)*8. Global src matches.
  int sr0 = (w * 2 + 0) * 16 + (lane >> 2);
  int sr1 = (w * 2 + 1) * 16 + (lane >> 2);
  int scol = (lane & 3) * 8;

  const u16* a0 = Abase + (size_t)sr0 * K_TOT + scol;
  const u16* a1 = Abase + (size_t)sr1 * K_TOT + scol;
  const u16* b0 = Bbase + (size_t)sr0 * K_TOT + scol;
  const u16* b1 = Bbase + (size_t)sr1 * K_TOT + scol;

  u16* sA0 = sA + (w * 2 + 0) * 512;
  u16* sA1 = sA + (w * 2 + 1) * 512;
  u16* sB0 = sB + (w * 2 + 0) * 512;
  u16* sB1 = sB + (w * 2 + 1) * 512;

  int arow = wr * 64 + (lane & 15);
  int brow = wc * 64 + (lane & 15);
  int kof = (lane >> 4) * 8;  // bf16 elems

  for (int k0 = 0; k0 < K_TOT; k0 += BK) {
    __builtin_amdgcn_global_load_lds(
        (const __attribute__((address_space(1))) uint32_t*)(a0 + k0),
        (__attribute__((address_space(3))) uint32_t*)sA0, 16, 0, 0);
    __builtin_amdgcn_global_load_lds(
        (const __attribute__((address_space(1))) uint32_t*)(a1 + k0),
        (__attribute__((address_space(3))) uint32_t*)sA1, 16, 0, 0);
    __builtin_amdgcn_global_load_lds(
        (const __attribute__((address_space(1))) uint32_t*)(b0 + k0),
        (__attribute__((address_space(3))) uint32_t*)sB0, 16, 0, 0);
    __builtin_amdgcn_global_load_lds(
        (const __attribute__((address_space(1))) uint32_t*)(b1 + k0),
        (__attribute__((address_space(3))) uint32_t*)sB1, 16, 0, 0);
    __syncthreads();

    bf16x8 af[4], bfr[4];
#pragma unroll
    for (int m = 0; m < 4; ++m)
      af[m] = *(const bf16x8*)(sA + (arow + m * 16) * BK + kof);
#pragma unroll
    for (int n = 0; n < 4; ++n)
      bfr[n] = *(const bf16x8*)(sB + (brow + n * 16) * BK + kof);

#pragma unroll
    for (int m = 0; m < 4; ++m)
#pragma unroll
      for (int n = 0; n < 4; ++n)
        acc[m][n] = __builtin_amdgcn_mfma_f32_16x16x32_bf16(af[m], bfr[n], acc[m][n], 0, 0, 0);
    __syncthreads();
  }

  // epilogue: C/D layout col=lane&15, row=(lane>>4)*4+j (m89-verified)
  int col = lane & 15;
  int rb = (lane >> 4) * 4;
#pragma unroll
  for (int n = 0; n < 4; ++n) {
    int gn = bn * BN + wc * 64 + n * 16 + col;
    float bs = bias[gn];
#pragma unroll
    for (int m = 0; m < 4; ++m) {
      int gm = bm * BM + wr * 64 + m * 16 + rb;
#pragma unroll
      for (int j = 0; j < 4; ++j)
        C[(size_t)(gm + j) * N_TOT + gn] = acc[m][n][j] + bs;
    }
  }
}

__global__ void fill_kernel(float* p, int n, float v) {
  int stride = gridDim.x * blockDim.x;
  for (int i = blockIdx.x * blockDim.x + threadIdx.x; i < n; i += stride) p[i] = v;
}

extern "C" void kernel_launch(void* const* d_in, const int* in_sizes, int n_in,
                              void* d_out, int out_size, void* d_ws, size_t ws_size,
                              hipStream_t stream) {
  const float* x = (const float*)d_in[0];
  const int* wp = (const int*)d_in[1];
  const float* sc = (const float*)d_in[2];
  const float* bias = (const float*)d_in[3];
  float* out = (float*)d_out;

  size_t xb_bytes = (size_t)M_TOT * K_TOT * 2;  // 64 MiB
  size_t wb_bytes = (size_t)N_TOT * K_TOT * 2;  // 32 MiB
  if (ws_size < xb_bytes + wb_bytes) {
    // diagnosable sentinel: absmax ~12345 => workspace too small
    fill_kernel<<<2048, 256, 0, stream>>>(out, out_size, 12345.0f);
    return;
  }
  u16* xb = (u16*)d_ws;
  u16* wb = (u16*)((char*)d_ws + xb_bytes);

  cvt_x_kernel<<<2048, 256, 0, stream>>>(x, xb, M_TOT * K_TOT / 8);
  dequant_w_kernel<<<2048, 256, 0, stream>>>(wp, sc, wb);
  gemm_bf16_kernel<<<(M_TOT / BM) * (N_TOT / BN), 256, 0, stream>>>(xb, wb, bias, out);
}

// Round 2
// 313.251 us; speedup vs baseline: 1.1870x; 1.1870x over previous
//
#include <hip/hip_runtime.h>
#include <stdint.h>

#define M_TOT 8192
#define K_TOT 4096
#define N_TOT 4096
#define GROUPQ 32

#define BM 256
#define BN 256
#define BK 32
#define NT (K_TOT / BK)   // 128 K-tiles

typedef __bf16 bf16x8 __attribute__((ext_vector_type(8)));
typedef float f32x4 __attribute__((ext_vector_type(4)));
typedef unsigned short u16;
typedef unsigned short u16x8 __attribute__((ext_vector_type(8)));

__device__ __forceinline__ u16 f2bf_rne(float f) {
  union { float f; uint32_t u; } v; v.f = f;
  uint32_t u = v.u;
  uint32_t r = (u + 0x7FFFu + ((u >> 16) & 1u)) >> 16;  // round-nearest-even
  return (u16)r;
}

// ---- prepass 1: x fp32 -> bf16 ----
__global__ void cvt_x_kernel(const float* __restrict__ x, u16* __restrict__ xb, int n8) {
  int stride = gridDim.x * blockDim.x;
  for (int i = blockIdx.x * blockDim.x + threadIdx.x; i < n8; i += stride) {
    const float4* p = (const float4*)(x + (size_t)i * 8);
    float4 a = p[0];
    float4 b = p[1];
    u16x8 o;
    o[0] = f2bf_rne(a.x); o[1] = f2bf_rne(a.y); o[2] = f2bf_rne(a.z); o[3] = f2bf_rne(a.w);
    o[4] = f2bf_rne(b.x); o[5] = f2bf_rne(b.y); o[6] = f2bf_rne(b.z); o[7] = f2bf_rne(b.w);
    *(u16x8*)(xb + (size_t)i * 8) = o;
  }
}

// ---- prepass 2: dequant packed nibbles -> bf16 W[N][K] row-major ----
__global__ void dequant_w_kernel(const int* __restrict__ wp, const float* __restrict__ sc,
                                 u16* __restrict__ wb) {
  const int KH = K_TOT / 2;
  const int total = N_TOT * KH / 8;
  int stride = gridDim.x * blockDim.x;
  for (int t = blockIdx.x * blockDim.x + threadIdx.x; t < total; t += stride) {
    int base = t * 8;
    int o = base >> 11;
    int ci = base & 2047;
    int e0 = ci * 2;
    float scale = sc[o * (K_TOT / GROUPQ) + (e0 >> 5)];
    int4 p0 = *(const int4*)(wp + base);
    int4 p1 = *(const int4*)(wp + base + 4);
    int v[8] = {p0.x, p0.y, p0.z, p0.w, p1.x, p1.y, p1.z, p1.w};
    u16x8 oA, oB;
#pragma unroll
    for (int j = 0; j < 8; ++j) {
      float lo = (float)((v[j] & 0xF) - 8) * scale;
      float hi = (float)(((v[j] >> 4) & 0xF) - 8) * scale;
      u16 lob = f2bf_rne(lo), hib = f2bf_rne(hi);
      if (j < 4) { oA[2 * j] = lob; oA[2 * j + 1] = hib; }
      else       { oB[2 * (j - 4)] = lob; oB[2 * (j - 4) + 1] = hib; }
    }
    u16* dst = wb + (size_t)o * K_TOT + e0;
    *(u16x8*)dst = oA;
    *(u16x8*)(dst + 8) = oB;
  }
}

// ---- main GEMM: 256x256 tile, BK=32, 8 waves, 3-deep LDS ring, 2-phase
// counted-vmcnt pipeline (T2 swizzle + T3/T4 phases + T5 setprio) ----
__global__ __launch_bounds__(512, 2) void gemm_bf16_kernel(
    const u16* __restrict__ A, const u16* __restrict__ Bt,
    const float* __restrict__ bias, float* __restrict__ C) {
  __shared__ alignas(16) u16 sA[3][BM * BK];  // 3 x 16 KiB
  __shared__ alignas(16) u16 sB[3][BN * BK];  // 3 x 16 KiB  (96 KiB total)

  const int ntn = N_TOT / BN;            // 16
  int wg = blockIdx.x, nwg = gridDim.x;  // 512, %8==0
  int cpx = nwg >> 3;
  int swz = (wg & 7) * cpx + (wg >> 3);  // bijective XCD swizzle
  int bm = swz / ntn, bn = swz % ntn;

  int tid = threadIdx.x, wid = tid >> 6, lane = tid & 63;
  int wr = wid >> 2, wc = wid & 3;       // 2M x 4N waves

  // ---- staging: gl_lds writes linear (base + lane*16B); source is
  // pre-swizzled so LDS chunk cl holds global chunk cl ^ ((row>>1)&3) ----
  int srow0 = (wid * 2) * 16 + (lane >> 2);
  int srow1 = (wid * 2 + 1) * 16 + (lane >> 2);
  int cl = lane & 3;
  int gch0 = (cl ^ ((srow0 >> 1) & 3)) * 8;   // element offset of fetched 16B chunk
  int gch1 = (cl ^ ((srow1 >> 1) & 3)) * 8;
  const u16* aS0 = A + (size_t)(bm * BM + srow0) * K_TOT + gch0;
  const u16* aS1 = A + (size_t)(bm * BM + srow1) * K_TOT + gch1;
  const u16* bS0 = Bt + (size_t)(bn * BN + srow0) * K_TOT + gch0;
  const u16* bS1 = Bt + (size_t)(bn * BN + srow1) * K_TOT + gch1;
  int ldst0 = (wid * 2) * 16 * BK;       // u16-element LDS base of instr 0
  int ldst1 = (wid * 2 + 1) * 16 * BK;

  auto stageA = [&](int ke, int b) {
    __builtin_amdgcn_global_load_lds(
        (const __attribute__((address_space(1))) uint32_t*)(aS0 + ke),
        (__attribute__((address_space(3))) uint32_t*)(&sA[b][ldst0]), 16, 0, 0);
    __builtin_amdgcn_global_load_lds(
        (const __attribute__((address_space(1))) uint32_t*)(aS1 + ke),
        (__attribute__((address_space(3))) uint32_t*)(&sA[b][ldst1]), 16, 0, 0);
  };
  auto stageB = [&](int ke, int b) {
    __builtin_amdgcn_global_load_lds(
        (const __attribute__((address_space(1))) uint32_t*)(bS0 + ke),
        (__attribute__((address_space(3))) uint32_t*)(&sB[b][ldst0]), 16, 0, 0);
    __builtin_amdgcn_global_load_lds(
        (const __attribute__((address_space(1))) uint32_t*)(bS1 + ke),
        (__attribute__((address_space(3))) uint32_t*)(&sB[b][ldst1]), 16, 0, 0);
  };

  // ---- reader offsets (swizzled read; same involution as source) ----
  int rr = lane & 15, rc = lane >> 4;
  int xorv = (rc ^ ((rr >> 1) & 3)) * 8;
  int abase = (wr * 128 + rr) * BK + xorv;
  int bbase = (wc * 64 + rr) * BK + xorv;

  f32x4 acc[8][4] = {};

  // prologue: stage tiles 0,1; wait tile 0 (allow tile 1's 4 in flight)
  stageA(0, 0); stageB(0, 0);
  stageA(BK, 1); stageB(BK, 1);
  asm volatile("s_waitcnt vmcnt(4)" ::: "memory");
  __builtin_amdgcn_s_barrier();

  for (int t = 0; t < NT; ++t) {
    int bt = t % 3;
    int bs = (t + 2) % 3;          // never == bt or (t+1)%3 -> race-free
    int ks = (t + 2) * BK;
    const u16* cA = sA[bt];
    const u16* cB = sB[bt];
    bool pf = (t + 2) < NT;

    // ---- phase 1: B frags (held both phases) + A m0..3 || stage A(t+2) ----
    bf16x8 bfr[4], af[4];
#pragma unroll
    for (int n = 0; n < 4; ++n) bfr[n] = *(const bf16x8*)(cB + bbase + n * 16 * BK);
#pragma unroll
    for (int m = 0; m < 4; ++m) af[m] = *(const bf16x8*)(cA + abase + m * 16 * BK);
    if (pf) stageA(ks, bs);
    __builtin_amdgcn_s_barrier();
    asm volatile("s_waitcnt lgkmcnt(0)" ::: "memory");
    __builtin_amdgcn_sched_barrier(0);
    __builtin_amdgcn_s_setprio(1);
#pragma unroll
    for (int m = 0; m < 4; ++m)
#pragma unroll
      for (int n = 0; n < 4; ++n)
        acc[m][n] = __builtin_amdgcn_mfma_f32_16x16x32_bf16(af[m], bfr[n], acc[m][n], 0, 0, 0);
    __builtin_amdgcn_s_setprio(0);
    __builtin_amdgcn_s_barrier();

    // ---- phase 2: A m4..7 || stage B(t+2); counted vmcnt at boundary ----
#pragma unroll
    for (int m = 0; m < 4; ++m) af[m] = *(const bf16x8*)(cA + abase + (m + 4) * 16 * BK);
    if (pf) stageB(ks, bs);
    __builtin_amdgcn_s_barrier();
    asm volatile("s_waitcnt lgkmcnt(0)" ::: "memory");
    __builtin_amdgcn_sched_barrier(0);
    __builtin_amdgcn_s_setprio(1);
#pragma unroll
    for (int m = 0; m < 4; ++m)
#pragma unroll
      for (int n = 0; n < 4; ++n)
        acc[m + 4][n] = __builtin_amdgcn_mfma_f32_16x16x32_bf16(af[m], bfr[n], acc[m + 4][n], 0, 0, 0);
    __builtin_amdgcn_s_setprio(0);
    if (pf) { asm volatile("s_waitcnt vmcnt(4)" ::: "memory"); }  // t+1 landed; t+2's 4 stay in flight
    else    { asm volatile("s_waitcnt vmcnt(0)" ::: "memory"); }  // tail drain
    __builtin_amdgcn_s_barrier();
  }

  // ---- epilogue: C/D layout col=lane&15, row=(lane>>4)*4+j ----
  int col = lane & 15;
  int rb = (lane >> 4) * 4;
#pragma unroll
  for (int n = 0; n < 4; ++n) {
    int gn = bn * BN + wc * 64 + n * 16 + col;
    float bsv = bias[gn];
#pragma unroll
    for (int m = 0; m < 8; ++m) {
      int gm = bm * BM + wr * 128 + m * 16 + rb;
#pragma unroll
      for (int j = 0; j < 4; ++j)
        C[(size_t)(gm + j) * N_TOT + gn] = acc[m][n][j] + bsv;
    }
  }
}

__global__ void fill_kernel(float* p, int n, float v) {
  int stride = gridDim.x * blockDim.x;
  for (int i = blockIdx.x * blockDim.x + threadIdx.x; i < n; i += stride) p[i] = v;
}

extern "C" void kernel_launch(void* const* d_in, const int* in_sizes, int n_in,
                              void* d_out, int out_size, void* d_ws, size_t ws_size,
                              hipStream_t stream) {
  const float* x = (const float*)d_in[0];
  const int* wp = (const int*)d_in[1];
  const float* sc = (const float*)d_in[2];
  const float* bias = (const float*)d_in[3];
  float* out = (float*)d_out;

  size_t xb_bytes = (size_t)M_TOT * K_TOT * 2;  // 64 MiB
  size_t wb_bytes = (size_t)N_TOT * K_TOT * 2;  // 32 MiB
  if (ws_size < xb_bytes + wb_bytes) {
    fill_kernel<<<2048, 256, 0, stream>>>(out, out_size, 12345.0f);
    return;
  }
  u16* xb = (u16*)d_ws;
  u16* wb = (u16*)((char*)d_ws + xb_bytes);

  cvt_x_kernel<<<2048, 256, 0, stream>>>(x, xb, M_TOT * K_TOT / 8);
  dequant_w_kernel<<<2048, 256, 0, stream>>>(wp, sc, wb);
  gemm_bf16_kernel<<<(M_TOT / BM) * (N_TOT / BN), 512, 0, stream>>>(xb, wb, bias, out);
}